// Round 1
// baseline (81.433 us; speedup 1.0000x reference)
//
#include <hip/hip_runtime.h>
#include <math.h>

#define NV 65536
#define NE 4096
#define NP 4096
#define NT 512
#define SENTF 1000000000.0f
#define BIGF 1e30f

// ---------------- wave(64) reduction helpers ----------------
__device__ __forceinline__ float waveMinF(float v) {
    #pragma unroll
    for (int o = 32; o; o >>= 1) v = fminf(v, __shfl_xor(v, o, 64));
    return v;
}
__device__ __forceinline__ float waveMaxF(float v) {
    #pragma unroll
    for (int o = 32; o; o >>= 1) v = fmaxf(v, __shfl_xor(v, o, 64));
    return v;
}
__device__ __forceinline__ int waveSumI(int v) {
    #pragma unroll
    for (int o = 32; o; o >>= 1) v += __shfl_xor(v, o, 64);
    return v;
}
__device__ __forceinline__ int waveMinI(int v) {
    #pragma unroll
    for (int o = 32; o; o >>= 1) v = min(v, __shfl_xor(v, o, 64));
    return v;
}
__device__ __forceinline__ int waveMaxI(int v) {
    #pragma unroll
    for (int o = 32; o; o >>= 1) v = max(v, __shfl_xor(v, o, 64));
    return v;
}

// ---------------- kernel 1: per-edge params ----------------
__global__ void edge_kernel(const float* __restrict__ verts,
                            const int*   __restrict__ edges,
                            float* __restrict__ ea,   float* __restrict__ eb,
                            float* __restrict__ exmn, float* __restrict__ exmx,
                            float* __restrict__ eymn, float* __restrict__ eymx) {
    int e = blockIdx.x * blockDim.x + threadIdx.x;
    if (e >= NE) return;
    int i0 = edges[2 * e + 0];
    int i1 = edges[2 * e + 1];
    float x0 = verts[3 * i0 + 0], y0 = verts[3 * i0 + 1];
    float x1 = verts[3 * i1 + 0], y1 = verts[3 * i1 + 1];
    float a = (y0 - y1) / (x0 - x1);
    float b = y0 - a * x0;
    ea[e] = a; eb[e] = b;
    exmn[e] = fminf(x0, x1); exmx[e] = fmaxf(x0, x1);
    eymn[e] = fminf(y0, y1); eymx[e] = fmaxf(y0, y1);
}

// ---------------- kernel 2: one wave per point ----------------
__global__ __launch_bounds__(256) void point_kernel(
        const float* __restrict__ verts,
        const float* __restrict__ tab,      // (NT,7)
        const int*   __restrict__ listAll,
        const float* __restrict__ ea,   const float* __restrict__ eb,
        const float* __restrict__ exmn, const float* __restrict__ exmx,
        const float* __restrict__ eymn, const float* __restrict__ eymx,
        float* __restrict__ mOut, int* __restrict__ validOut) {
    int wid  = threadIdx.x >> 6;
    int lane = threadIdx.x & 63;
    int p = blockIdx.x * 4 + wid;
    if (p >= NP) return;

    int   vi = listAll[p];
    float px = verts[3 * vi + 0];
    float py = verts[3 * vi + 1];

    // ---- phase 1: first edge index with px strictly inside (xmn, xmx) ----
    int minIdx = NE;  // sentinel
    for (int e = lane; e < NE; e += 64) {
        float mn = exmn[e], mx = exmx[e];
        if (px > mn && px < mx) { minIdx = e; break; }  // ascending per lane -> first hit is lane min
    }
    minIdx = waveMinI(minIdx);
    int idx = (minIdx >= NE) ? (NE - 1) : minIdx;

    float exposeY = ea[idx] * px + eb[idx];
    float L1 = fabsf(py - exposeY);
    float cy = 0.5f * (py + exposeY);
    float cx = px;

    // ---- phase 2: condB reductions over all edges ----
    int   n = 0, hasS = 0, hasI = 0;
    float xallmx = -SENTF, xallmn = SENTF;
    float xs = SENTF, xinf = -SENTF;
    for (int e = lane; e < NE; e += 64) {
        float ymn = eymn[e], ymx = eymx[e];
        if (cy > ymn && cy < ymx) {
            float xi = (cy - eb[e]) / ea[e];
            n++;
            xallmx = fmaxf(xallmx, xi);
            xallmn = fminf(xallmn, xi);
            if (xi >= cx) { xs   = fminf(xs,   xi); hasS = 1; }
            else          { xinf = fmaxf(xinf, xi); hasI = 1; }
        }
    }
    n      = waveSumI(n);
    xallmx = waveMaxF(xallmx);
    xallmn = waveMinF(xallmn);
    xs     = waveMinF(xs);
    xinf   = waveMaxF(xinf);
    hasS   = waveMaxI(hasS);
    hasI   = waveMaxI(hasI);

    bool valid = (n == 2) || ((n > 2) && hasS && hasI);
    float dx = (n == 2) ? (xallmx - xallmn) : (xs - xinf);
    float L2 = fabsf(dx);
    float d1 = fabsf(cy - 1.0f);
    float d2 = fabsf(px - 1.0f);

    // ---- phase 3: min over table rows ----
    float pm = INFINITY;
    for (int t = lane; t < NT; t += 64) {
        const float* r = tab + 7 * t;
        float al = fabsf(L1 - r[3]) + fabsf(L2 - r[4]) +
                   fabsf(d1 - r[5]) + fabsf(d2 - r[6]);
        pm = fminf(pm, al);
    }
    pm = waveMinF(pm);

    if (lane == 0) {
        mOut[p]     = valid ? pm : BIGF;
        validOut[p] = valid ? 1 : 0;
    }
}

// ---------------- kernel 3: cummin + masked sum (single block) ----------------
__global__ __launch_bounds__(1024) void scan_kernel(const float* __restrict__ m,
                                                    const int*   __restrict__ valid,
                                                    float* __restrict__ out) {
    __shared__ float sc[1024];
    __shared__ float ssum[16];
    int t = threadIdx.x;

    float v[4]; int vl[4];
    #pragma unroll
    for (int j = 0; j < 4; j++) { v[j] = m[4 * t + j]; vl[j] = valid[4 * t + j]; }
    float cmin = fminf(fminf(v[0], v[1]), fminf(v[2], v[3]));
    sc[t] = cmin;
    __syncthreads();

    // inclusive min-scan over per-thread chunk mins
    for (int off = 1; off < 1024; off <<= 1) {
        float prev = (t >= off) ? sc[t - off] : INFINITY;
        __syncthreads();
        sc[t] = fminf(sc[t], prev);
        __syncthreads();
    }
    float run = (t == 0) ? INFINITY : sc[t - 1];

    float sum = 0.0f;
    #pragma unroll
    for (int j = 0; j < 4; j++) {
        run = fminf(run, v[j]);
        if (vl[j]) sum += run;
    }
    // block sum reduction
    #pragma unroll
    for (int o = 32; o; o >>= 1) sum += __shfl_xor(sum, o, 64);
    if ((t & 63) == 0) ssum[t >> 6] = sum;
    __syncthreads();
    if (t == 0) {
        float s = 0.0f;
        for (int i = 0; i < 16; i++) s += ssum[i];
        out[0] = s;
    }
}

extern "C" void kernel_launch(void* const* d_in, const int* in_sizes, int n_in,
                              void* d_out, int out_size, void* d_ws, size_t ws_size,
                              hipStream_t stream) {
    const float* verts   = (const float*)d_in[0];
    const float* tab     = (const float*)d_in[1];
    const int*   edges   = (const int*)d_in[2];
    const int*   listAll = (const int*)d_in[3];

    float* ws   = (float*)d_ws;
    float* ea   = ws;
    float* eb   = ea   + NE;
    float* exmn = eb   + NE;
    float* exmx = exmn + NE;
    float* eymn = exmx + NE;
    float* eymx = eymn + NE;
    float* mArr = eymx + NE;
    int*   vArr = (int*)(mArr + NP);

    edge_kernel<<<(NE + 255) / 256, 256, 0, stream>>>(verts, edges, ea, eb, exmn, exmx, eymn, eymx);
    point_kernel<<<NP / 4, 256, 0, stream>>>(verts, tab, listAll,
                                             ea, eb, exmn, exmx, eymn, eymx,
                                             mArr, vArr);
    scan_kernel<<<1, 1024, 0, stream>>>(mArr, vArr, (float*)d_out);
}

// Round 2
// 59.446 us; speedup vs baseline: 1.3699x; 1.3699x over previous
//
#include <hip/hip_runtime.h>
#include <math.h>

#define NV 65536
#define NE 4096
#define NP 4096
#define NT 512
#define SENTF 1000000000.0f
#define BIGF 1e30f

// ---------------- wave(64) reduction helpers ----------------
__device__ __forceinline__ float waveMinF(float v) {
    #pragma unroll
    for (int o = 32; o; o >>= 1) v = fminf(v, __shfl_xor(v, o, 64));
    return v;
}
__device__ __forceinline__ float waveMaxF(float v) {
    #pragma unroll
    for (int o = 32; o; o >>= 1) v = fmaxf(v, __shfl_xor(v, o, 64));
    return v;
}
__device__ __forceinline__ int waveSumI(int v) {
    #pragma unroll
    for (int o = 32; o; o >>= 1) v += __shfl_xor(v, o, 64);
    return v;
}
__device__ __forceinline__ int waveMinI(int v) {
    #pragma unroll
    for (int o = 32; o; o >>= 1) v = min(v, __shfl_xor(v, o, 64));
    return v;
}

// ---------------- kernel 1: per-edge params (packed) + table repack ----------------
__global__ void prep_kernel(const float* __restrict__ verts,
                            const int*   __restrict__ edges,
                            const float* __restrict__ tab,
                            float*  __restrict__ ea,  float*  __restrict__ eb,
                            float2* __restrict__ pk2, float4* __restrict__ pk4,
                            float4* __restrict__ tb4) {
    int e = blockIdx.x * blockDim.x + threadIdx.x;
    if (e < NT) {
        const float* r = tab + 7 * e;
        tb4[e] = make_float4(r[3], r[4], r[5], r[6]);
    }
    if (e >= NE) return;
    int i0 = edges[2 * e + 0];
    int i1 = edges[2 * e + 1];
    float x0 = verts[3 * i0 + 0], y0 = verts[3 * i0 + 1];
    float x1 = verts[3 * i1 + 0], y1 = verts[3 * i1 + 1];
    float a = (y0 - y1) / (x0 - x1);
    float b = y0 - a * x0;
    ea[e] = a; eb[e] = b;
    pk2[e] = make_float2(fminf(x0, x1), fmaxf(x0, x1));
    pk4[e] = make_float4(fminf(y0, y1), fmaxf(y0, y1), a, b);
}

// ---------------- kernel 2: TWO waves per point ----------------
// block = 256 threads = 4 waves = 2 points; wave pair (half=0,1) splits the edge range.
__global__ __launch_bounds__(256) void point_kernel(
        const float*  __restrict__ verts,
        const int*    __restrict__ listAll,
        const float*  __restrict__ ea,  const float*  __restrict__ eb,
        const float2* __restrict__ pk2, const float4* __restrict__ pk4,
        const float4* __restrict__ tb4,
        float* __restrict__ mOut, int* __restrict__ validOut) {
    __shared__ int   sIdx[2][2];
    __shared__ float sMx[2][2], sMn[2][2], sXs[2][2], sXi[2][2];
    __shared__ int   sPk[2][2];
    __shared__ float sPm[2][2];

    int tid  = threadIdx.x;
    int lane = tid & 63;
    int wid  = tid >> 6;          // 0..3
    int pr   = wid >> 1;          // pair in block: 0..1
    int half = wid & 1;           // which half of edge range
    int p    = blockIdx.x * 2 + pr;

    int   vi = listAll[p];
    float px = verts[3 * vi + 0];
    float py = verts[3 * vi + 1];

    const int base = half * (NE / 2);
    const int end  = base + (NE / 2);

    // ---- phase 1: first edge with px strictly inside (xmn, xmx), over my half ----
    int minIdx = NE;
    for (int e = base + lane; e < end; e += 64) {
        float2 q = pk2[e];
        if (px > q.x && px < q.y) { minIdx = e; break; }
    }
    minIdx = waveMinI(minIdx);
    if (lane == 0) sIdx[pr][half] = minIdx;
    __syncthreads();
    int idx = min(sIdx[pr][0], sIdx[pr][1]);
    if (idx >= NE) idx = NE - 1;

    float exposeY = ea[idx] * px + eb[idx];
    float L1 = fabsf(py - exposeY);
    float cy = 0.5f * (py + exposeY);
    float cx = px;

    // ---- phase 2: condB reductions over my half (float4 packed, unrolled) ----
    int   n = 0, hasS = 0, hasI = 0;
    float xallmx = -SENTF, xallmn = SENTF;
    float xs = SENTF, xinf = -SENTF;
    #pragma unroll 4
    for (int e = base + lane; e < end; e += 64) {
        float4 q = pk4[e];                 // (ymn, ymx, a, b)
        if (cy > q.x && cy < q.y) {
            float xi = (cy - q.w) / q.z;   // exact IEEE divide, matches reference
            n++;
            xallmx = fmaxf(xallmx, xi);
            xallmn = fminf(xallmn, xi);
            if (xi >= cx) { xs   = fminf(xs,   xi); hasS = 1; }
            else          { xinf = fmaxf(xinf, xi); hasI = 1; }
        }
    }
    // packed int reduce: n in bits 0..13, hasS count bits 16..23, hasI bits 24..31
    int packed = n | (hasS << 16) | (hasI << 24);
    packed = waveSumI(packed);
    xallmx = waveMaxF(xallmx);
    xallmn = waveMinF(xallmn);
    xs     = waveMinF(xs);
    xinf   = waveMaxF(xinf);
    if (lane == 0) {
        sPk[pr][half] = packed;
        sMx[pr][half] = xallmx; sMn[pr][half] = xallmn;
        sXs[pr][half] = xs;     sXi[pr][half] = xinf;
    }
    __syncthreads();
    {
        int pkA = sPk[pr][0], pkB = sPk[pr][1];
        n    = (pkA & 0xFFFF) + (pkB & 0xFFFF);
        hasS = ((pkA >> 16) & 0xFF) + ((pkB >> 16) & 0xFF);
        hasI = ((pkA >> 24) & 0xFF) + ((pkB >> 24) & 0xFF);
        xallmx = fmaxf(sMx[pr][0], sMx[pr][1]);
        xallmn = fminf(sMn[pr][0], sMn[pr][1]);
        xs     = fminf(sXs[pr][0], sXs[pr][1]);
        xinf   = fmaxf(sXi[pr][0], sXi[pr][1]);
    }

    bool valid = (n == 2) || ((n > 2) && (hasS > 0) && (hasI > 0));
    float dx = (n == 2) ? (xallmx - xallmn) : (xs - xinf);
    float L2 = fabsf(dx);
    float d1 = fabsf(cy - 1.0f);
    float d2 = fabsf(px - 1.0f);

    // ---- phase 3: min over my half of the table (float4 packed) ----
    float pm = INFINITY;
    #pragma unroll
    for (int k = 0; k < 4; k++) {
        int t = half * (NT / 2) + k * 64 + lane;
        float4 r = tb4[t];
        float al = fabsf(L1 - r.x) + fabsf(L2 - r.y) +
                   fabsf(d1 - r.z) + fabsf(d2 - r.w);
        pm = fminf(pm, al);
    }
    pm = waveMinF(pm);
    if (lane == 0) sPm[pr][half] = pm;
    __syncthreads();

    if (half == 0 && lane == 0) {
        float pmin = fminf(sPm[pr][0], sPm[pr][1]);
        mOut[p]     = valid ? pmin : BIGF;
        validOut[p] = valid ? 1 : 0;
    }
}

// ---------------- kernel 3: cummin + masked sum (single block, shuffle scans) ----------------
__global__ __launch_bounds__(1024) void scan_kernel(const float* __restrict__ m,
                                                    const int*   __restrict__ valid,
                                                    float* __restrict__ out) {
    __shared__ float wAgg[16];
    __shared__ float wSum[16];
    int t = threadIdx.x;
    int lane = t & 63, wid = t >> 6;

    float v[4]; int vl[4];
    #pragma unroll
    for (int j = 0; j < 4; j++) { v[j] = m[4 * t + j]; vl[j] = valid[4 * t + j]; }
    float cmin = fminf(fminf(v[0], v[1]), fminf(v[2], v[3]));

    // inclusive wave min-scan via shfl_up
    float inc = cmin;
    #pragma unroll
    for (int o = 1; o < 64; o <<= 1) {
        float u = __shfl_up(inc, o, 64);
        if (lane >= o) inc = fminf(inc, u);
    }
    if (lane == 63) wAgg[wid] = inc;
    __syncthreads();

    float wavePrefix = INFINITY;
    for (int i = 0; i < wid; i++) wavePrefix = fminf(wavePrefix, wAgg[i]);
    float excl = __shfl_up(inc, 1, 64);
    if (lane == 0) excl = INFINITY;
    float run = fminf(wavePrefix, excl);

    float sum = 0.0f;
    #pragma unroll
    for (int j = 0; j < 4; j++) {
        run = fminf(run, v[j]);
        if (vl[j]) sum += run;
    }
    #pragma unroll
    for (int o = 32; o; o >>= 1) sum += __shfl_xor(sum, o, 64);
    if (lane == 0) wSum[wid] = sum;
    __syncthreads();
    if (t == 0) {
        float s = 0.0f;
        for (int i = 0; i < 16; i++) s += wSum[i];
        out[0] = s;
    }
}

extern "C" void kernel_launch(void* const* d_in, const int* in_sizes, int n_in,
                              void* d_out, int out_size, void* d_ws, size_t ws_size,
                              hipStream_t stream) {
    const float* verts   = (const float*)d_in[0];
    const float* tab     = (const float*)d_in[1];
    const int*   edges   = (const int*)d_in[2];
    const int*   listAll = (const int*)d_in[3];

    // workspace layout (16-B aligned first)
    char* ws = (char*)d_ws;
    float4* pk4 = (float4*)ws;                     ws += NE * sizeof(float4);
    float4* tb4 = (float4*)ws;                     ws += NT * sizeof(float4);
    float2* pk2 = (float2*)ws;                     ws += NE * sizeof(float2);
    float*  ea  = (float*)ws;                      ws += NE * sizeof(float);
    float*  eb  = (float*)ws;                      ws += NE * sizeof(float);
    float*  mArr= (float*)ws;                      ws += NP * sizeof(float);
    int*    vArr= (int*)ws;

    prep_kernel<<<(NE + 255) / 256, 256, 0, stream>>>(verts, edges, tab, ea, eb, pk2, pk4, tb4);
    point_kernel<<<NP / 2, 256, 0, stream>>>(verts, listAll, ea, eb, pk2, pk4, tb4, mArr, vArr);
    scan_kernel<<<1, 1024, 0, stream>>>(mArr, vArr, (float*)d_out);
}

// Round 3
// 27.416 us; speedup vs baseline: 2.9703x; 2.1683x over previous
//
#include <hip/hip_runtime.h>
#include <math.h>

#define NV 65536
#define NE 4096
#define NP 4096
#define NT 512
#define SENTF 1000000000.0f
#define BIGF 1e30f

// ---------------- wave(64) reduction helpers ----------------
__device__ __forceinline__ float waveMinF(float v) {
    #pragma unroll
    for (int o = 32; o; o >>= 1) v = fminf(v, __shfl_xor(v, o, 64));
    return v;
}
__device__ __forceinline__ float waveMaxF(float v) {
    #pragma unroll
    for (int o = 32; o; o >>= 1) v = fmaxf(v, __shfl_xor(v, o, 64));
    return v;
}
__device__ __forceinline__ int waveSumI(int v) {
    #pragma unroll
    for (int o = 32; o; o >>= 1) v += __shfl_xor(v, o, 64);
    return v;
}
__device__ __forceinline__ int waveMinI(int v) {
    #pragma unroll
    for (int o = 32; o; o >>= 1) v = min(v, __shfl_xor(v, o, 64));
    return v;
}

// ---------------- kernel 1: per-edge params (packed) + table repack ----------------
__global__ void prep_kernel(const float* __restrict__ verts,
                            const int*   __restrict__ edges,
                            const float* __restrict__ tab,
                            float*  __restrict__ ea,  float*  __restrict__ eb,
                            float2* __restrict__ pk2, float4* __restrict__ pk4,
                            float4* __restrict__ tb4) {
    int e = blockIdx.x * blockDim.x + threadIdx.x;
    if (e < NT) {
        const float* r = tab + 7 * e;
        tb4[e] = make_float4(r[3], r[4], r[5], r[6]);
    }
    if (e >= NE) return;
    int i0 = edges[2 * e + 0];
    int i1 = edges[2 * e + 1];
    float x0 = verts[3 * i0 + 0], y0 = verts[3 * i0 + 1];
    float x1 = verts[3 * i1 + 0], y1 = verts[3 * i1 + 1];
    float a = (y0 - y1) / (x0 - x1);
    float b = y0 - a * x0;
    ea[e] = a; eb[e] = b;
    pk2[e] = make_float2(fminf(x0, x1), fmaxf(x0, x1));
    pk4[e] = make_float4(fminf(y0, y1), fmaxf(y0, y1), 1.0f / a, b);  // reciprocal hoisted
}

// ---------------- kernel 2: TWO waves per point ----------------
__global__ __launch_bounds__(256) void point_kernel(
        const float*  __restrict__ verts,
        const int*    __restrict__ listAll,
        const float*  __restrict__ ea,  const float*  __restrict__ eb,
        const float2* __restrict__ pk2, const float4* __restrict__ pk4,
        const float4* __restrict__ tb4,
        float* __restrict__ mOut, int* __restrict__ validOut) {
    __shared__ int   sIdx[2][2];
    __shared__ float sMx[2][2], sMn[2][2], sXs[2][2], sXi[2][2];
    __shared__ int   sPk[2][2];
    __shared__ float sPm[2][2];

    int tid  = threadIdx.x;
    int lane = tid & 63;
    int wid  = tid >> 6;          // 0..3
    int pr   = wid >> 1;          // pair in block: 0..1
    int half = wid & 1;           // which half of edge range
    int p    = blockIdx.x * 2 + pr;

    int   vi = listAll[p];
    float px = verts[3 * vi + 0];
    float py = verts[3 * vi + 1];

    const int base = half * (NE / 2);

    // ---- phase 1: first edge with px strictly inside (xmn, xmx), over my half ----
    // Iteration k's indices are all < iteration k+1's, so once ANY lane hits,
    // the wave-min of this iteration is the half-range argmax(condA). Expected
    // exit after 1 iteration (hit density ~1/3 per edge).
    int minIdx = NE;
    for (int it = 0; it < (NE / 2) / 64; ++it) {
        int e = base + it * 64 + lane;
        float2 q = pk2[e];
        bool hit = (px > q.x) && (px < q.y);
        if (hit) minIdx = e;
        if (__any(hit)) break;
    }
    minIdx = waveMinI(minIdx);
    if (lane == 0) sIdx[pr][half] = minIdx;
    __syncthreads();
    int idx = min(sIdx[pr][0], sIdx[pr][1]);
    if (idx >= NE) idx = NE - 1;

    float exposeY = ea[idx] * px + eb[idx];
    float L1 = fabsf(py - exposeY);
    float cy = 0.5f * (py + exposeY);
    float cx = px;

    // ---- phase 2: branchless condB reductions over my half ----
    int   n = 0, hasS = 0, hasI = 0;
    float xallmx = -SENTF, xallmn = SENTF;
    float xs = SENTF, xinf = -SENTF;
    #pragma unroll 8
    for (int e = base + lane; e < base + (NE / 2); e += 64) {
        float4 q = pk4[e];                     // (ymn, ymx, 1/a, b)
        bool  c  = (cy > q.x) && (cy < q.y);
        float xi = (cy - q.w) * q.z;
        n += c ? 1 : 0;
        xallmx = fmaxf(xallmx, c ? xi : -SENTF);
        xallmn = fminf(xallmn, c ? xi :  SENTF);
        bool sp = c && (xi >= cx);
        bool in_ = c && (xi <  cx);
        xs   = fminf(xs,   sp  ? xi :  SENTF);
        xinf = fmaxf(xinf, in_ ? xi : -SENTF);
        hasS |= sp ? 1 : 0;
        hasI |= in_ ? 1 : 0;
    }
    int packed = n | (hasS << 16) | (hasI << 24);
    packed = waveSumI(packed);
    xallmx = waveMaxF(xallmx);
    xallmn = waveMinF(xallmn);
    xs     = waveMinF(xs);
    xinf   = waveMaxF(xinf);
    if (lane == 0) {
        sPk[pr][half] = packed;
        sMx[pr][half] = xallmx; sMn[pr][half] = xallmn;
        sXs[pr][half] = xs;     sXi[pr][half] = xinf;
    }
    __syncthreads();
    {
        int pkA = sPk[pr][0], pkB = sPk[pr][1];
        n    = (pkA & 0xFFFF) + (pkB & 0xFFFF);
        hasS = ((pkA >> 16) & 0xFF) + ((pkB >> 16) & 0xFF);
        hasI = ((pkA >> 24) & 0xFF) + ((pkB >> 24) & 0xFF);
        xallmx = fmaxf(sMx[pr][0], sMx[pr][1]);
        xallmn = fminf(sMn[pr][0], sMn[pr][1]);
        xs     = fminf(sXs[pr][0], sXs[pr][1]);
        xinf   = fmaxf(sXi[pr][0], sXi[pr][1]);
    }

    bool valid = (n == 2) || ((n > 2) && (hasS > 0) && (hasI > 0));
    float dx = (n == 2) ? (xallmx - xallmn) : (xs - xinf);
    float L2 = fabsf(dx);
    float d1 = fabsf(cy - 1.0f);
    float d2 = fabsf(px - 1.0f);

    // ---- phase 3: min over my half of the table (float4 packed) ----
    float pm = INFINITY;
    #pragma unroll
    for (int k = 0; k < 4; k++) {
        int t = half * (NT / 2) + k * 64 + lane;
        float4 r = tb4[t];
        float al = fabsf(L1 - r.x) + fabsf(L2 - r.y) +
                   fabsf(d1 - r.z) + fabsf(d2 - r.w);
        pm = fminf(pm, al);
    }
    pm = waveMinF(pm);
    if (lane == 0) sPm[pr][half] = pm;
    __syncthreads();

    if (half == 0 && lane == 0) {
        float pmin = fminf(sPm[pr][0], sPm[pr][1]);
        mOut[p]     = valid ? pmin : BIGF;
        validOut[p] = valid ? 1 : 0;
    }
}

// ---------------- kernel 3: cummin + masked sum (single block, shuffle scans) ----------------
__global__ __launch_bounds__(1024) void scan_kernel(const float* __restrict__ m,
                                                    const int*   __restrict__ valid,
                                                    float* __restrict__ out) {
    __shared__ float wAgg[16];
    __shared__ float wSum[16];
    int t = threadIdx.x;
    int lane = t & 63, wid = t >> 6;

    float v[4]; int vl[4];
    #pragma unroll
    for (int j = 0; j < 4; j++) { v[j] = m[4 * t + j]; vl[j] = valid[4 * t + j]; }
    float cmin = fminf(fminf(v[0], v[1]), fminf(v[2], v[3]));

    // inclusive wave min-scan via shfl_up
    float inc = cmin;
    #pragma unroll
    for (int o = 1; o < 64; o <<= 1) {
        float u = __shfl_up(inc, o, 64);
        if (lane >= o) inc = fminf(inc, u);
    }
    if (lane == 63) wAgg[wid] = inc;
    __syncthreads();

    float wavePrefix = INFINITY;
    for (int i = 0; i < wid; i++) wavePrefix = fminf(wavePrefix, wAgg[i]);
    float excl = __shfl_up(inc, 1, 64);
    if (lane == 0) excl = INFINITY;
    float run = fminf(wavePrefix, excl);

    float sum = 0.0f;
    #pragma unroll
    for (int j = 0; j < 4; j++) {
        run = fminf(run, v[j]);
        if (vl[j]) sum += run;
    }
    #pragma unroll
    for (int o = 32; o; o >>= 1) sum += __shfl_xor(sum, o, 64);
    if (lane == 0) wSum[wid] = sum;
    __syncthreads();
    if (t == 0) {
        float s = 0.0f;
        for (int i = 0; i < 16; i++) s += wSum[i];
        out[0] = s;
    }
}

extern "C" void kernel_launch(void* const* d_in, const int* in_sizes, int n_in,
                              void* d_out, int out_size, void* d_ws, size_t ws_size,
                              hipStream_t stream) {
    const float* verts   = (const float*)d_in[0];
    const float* tab     = (const float*)d_in[1];
    const int*   edges   = (const int*)d_in[2];
    const int*   listAll = (const int*)d_in[3];

    // workspace layout (16-B aligned first)
    char* ws = (char*)d_ws;
    float4* pk4 = (float4*)ws;                     ws += NE * sizeof(float4);
    float4* tb4 = (float4*)ws;                     ws += NT * sizeof(float4);
    float2* pk2 = (float2*)ws;                     ws += NE * sizeof(float2);
    float*  ea  = (float*)ws;                      ws += NE * sizeof(float);
    float*  eb  = (float*)ws;                      ws += NE * sizeof(float);
    float*  mArr= (float*)ws;                      ws += NP * sizeof(float);
    int*    vArr= (int*)ws;

    prep_kernel<<<(NE + 255) / 256, 256, 0, stream>>>(verts, edges, tab, ea, eb, pk2, pk4, tb4);
    point_kernel<<<NP / 2, 256, 0, stream>>>(verts, listAll, ea, eb, pk2, pk4, tb4, mArr, vArr);
    scan_kernel<<<1, 1024, 0, stream>>>(mArr, vArr, (float*)d_out);
}